// Round 2
// baseline (56.615 us; speedup 1.0000x reference)
//
#include <hip/hip_runtime.h>
#include <hip/hip_bf16.h>

// Problem constants (from reference): B=16, S=512, H=768.
#define BB 16
#define SS 512
#define HH 768
#define H4 (HH / 4)   // 192 float4 per row

// Kernel 1: mask_len[b] = sum over masks[b, :]
__global__ __launch_bounds__(256) void masklen_kernel(const int* __restrict__ masks,
                                                      int* __restrict__ mlen) {
    const int b = blockIdx.x;
    int sum = 0;
    for (int i = threadIdx.x; i < SS; i += blockDim.x)
        sum += masks[b * SS + i];
    for (int off = 32; off > 0; off >>= 1)
        sum += __shfl_down(sum, off, 64);
    __shared__ int wsum[4];
    const int wid = threadIdx.x >> 6;
    const int lane = threadIdx.x & 63;
    if (lane == 0) wsum[wid] = sum;
    __syncthreads();
    if (threadIdx.x == 0) {
        int tot = 0;
        for (int w = 0; w < (int)(blockDim.x >> 6); ++w) tot += wsum[w];
        mlen[b] = tot;
    }
}

// Kernel 2: one block per (b, t); 192 threads each own one float4 column of H.
// span in {1,2,3} always (reference clamps to >=1, and valid t has t+1 <= S-1),
// so issue ALL 12 loads (4 layers x 3 rows, clamped) unconditionally and
// combine with branchless 0/1 weights -> max memory-level parallelism.
__global__ __launch_bounds__(192) void span_pool_kernel(const float* __restrict__ hidden,
                                                        const int* __restrict__ spans,
                                                        const int* __restrict__ mlen,
                                                        float* __restrict__ out) {
    const int t = blockIdx.x;
    const int b = blockIdx.y;
    const int h4 = threadIdx.x;  // 0..191

    float4 acc = make_float4(0.f, 0.f, 0.f, 0.f);

    const int ml = mlen[b];
    const bool valid = (t >= 1) && (t < ml - 1);
    if (valid) {
        const int span = spans[b * SS + t];
        const int start = t + 1;                      // <= S-1 when valid
        const int n = min(start + span, SS) - start;  // 1..3

        const int j0 = start;
        const int j1 = min(start + 1, SS - 1);
        const int j2 = min(start + 2, SS - 1);

        const float w1 = (n >= 2) ? 1.f : 0.f;
        const float w2 = (n >= 3) ? 1.f : 0.f;

        float4 v0[4], v1[4], v2[4];
        #pragma unroll
        for (int l = 0; l < 4; ++l) {
            const float4* base =
                (const float4*)(hidden) + ((size_t)(l * BB + b) * SS) * H4 + h4;
            v0[l] = base[(size_t)j0 * H4];
            v1[l] = base[(size_t)j1 * H4];
            v2[l] = base[(size_t)j2 * H4];
        }
        #pragma unroll
        for (int l = 0; l < 4; ++l) {
            acc.x += v0[l].x; acc.y += v0[l].y; acc.z += v0[l].z; acc.w += v0[l].w;
            acc.x = fmaf(w1, v1[l].x, acc.x); acc.y = fmaf(w1, v1[l].y, acc.y);
            acc.z = fmaf(w1, v1[l].z, acc.z); acc.w = fmaf(w1, v1[l].w, acc.w);
            acc.x = fmaf(w2, v2[l].x, acc.x); acc.y = fmaf(w2, v2[l].y, acc.y);
            acc.z = fmaf(w2, v2[l].z, acc.z); acc.w = fmaf(w2, v2[l].w, acc.w);
        }
        acc.x *= 0.25f; acc.y *= 0.25f; acc.z *= 0.25f; acc.w *= 0.25f;
    }

    float4* o = (float4*)(out) + ((size_t)(b * SS + t)) * H4;
    o[h4] = acc;
}

extern "C" void kernel_launch(void* const* d_in, const int* in_sizes, int n_in,
                              void* d_out, int out_size, void* d_ws, size_t ws_size,
                              hipStream_t stream) {
    const float* hidden = (const float*)d_in[0];  // [4,B,S,H] f32
    const int* spans    = (const int*)d_in[1];    // [B,S] i32
    const int* masks    = (const int*)d_in[2];    // [B,S] i32
    float* out          = (float*)d_out;          // [B,S,H] f32
    int* mlen           = (int*)d_ws;             // [B] i32 scratch

    masklen_kernel<<<dim3(BB), dim3(256), 0, stream>>>(masks, mlen);

    dim3 grid(SS, BB);
    span_pool_kernel<<<grid, dim3(192), 0, stream>>>(hidden, spans, mlen, out);
}

// Round 3
// 24.441 us; speedup vs baseline: 2.3164x; 2.3164x over previous
//
#include <hip/hip_runtime.h>
#include <hip/hip_bf16.h>

// Problem constants (from reference): B=16, S=512, H=768.
#define BB 16
#define SS 512
#define HH 768
#define H4 (HH / 4)    // 192 float4 per row
#define HS 64          // float4 columns per block (64 threads, 1 wave)
#define NHS (H4 / HS)  // 3 h-slices
#define TC 32          // tokens per chunk
#define NSC (SS / TC)  // 16 s-chunks

// One wave per (b, h-slice, s-chunk). Register sliding window over the
// layer-summed rows m[t+1], m[t+2], m[t+3]; each row of hidden is loaded
// exactly once per block (plus a 3-row halo at chunk boundaries).
__global__ __launch_bounds__(64) void span_pool_kernel(
    const float* __restrict__ hidden, const int* __restrict__ spans,
    const int* __restrict__ masks, float* __restrict__ out) {

    const int sc   = blockIdx.x;
    const int hs   = blockIdx.y;
    const int b    = blockIdx.z;
    const int lane = threadIdx.x;  // 0..63

    // mask_len[b] = sum(masks[b,:]) — fused per-block reduce (2 KB, L2-hot).
    int msum = 0;
    const int* mrow = masks + b * SS;
    #pragma unroll
    for (int i = 0; i < SS / 64; ++i) msum += mrow[lane + i * 64];
    #pragma unroll
    for (int off = 32; off; off >>= 1) msum += __shfl_down(msum, off, 64);
    const int ml = __shfl(msum, 0, 64);

    const int t0  = sc * TC;
    const int col = hs * HS + lane;              // this thread's float4 column
    const size_t LSTR = (size_t)BB * SS * H4;    // layer stride in float4

    const float4* hb = (const float4*)hidden + (size_t)b * SS * H4 + col;

    auto loadrow = [&](int j) {
        j = min(j, SS - 1);                      // clamped halo rows get weight 0
        const float4* p = hb + (size_t)j * H4;
        float4 a = p[0], c = p[LSTR], d = p[2 * LSTR], e = p[3 * LSTR];
        return make_float4(a.x + c.x + d.x + e.x, a.y + c.y + d.y + e.y,
                           a.z + c.z + d.z + e.z, a.w + c.w + d.w + e.w);
    };

    float4 m1 = loadrow(t0 + 1);
    float4 m2 = loadrow(t0 + 2);
    float4 m3 = loadrow(t0 + 3);

    float4* orow = (float4*)out + ((size_t)b * SS + t0) * H4 + col;
    const int* srow = spans + b * SS + t0;

    #pragma unroll 4
    for (int i = 0; i < TC; ++i) {
        const int t = t0 + i;
        float4 nxt = loadrow(t + 4);             // prefetch next window row
        const bool valid = (t >= 1) && (t < ml - 1);
        const int n = min(srow[i], SS - 1 - t);  // 1..3 when valid
        const float w1 = valid ? 0.25f : 0.0f;
        const float w2 = (valid && n >= 2) ? 0.25f : 0.0f;
        const float w3 = (valid && n >= 3) ? 0.25f : 0.0f;
        float4 r;
        r.x = w1 * m1.x + w2 * m2.x + w3 * m3.x;
        r.y = w1 * m1.y + w2 * m2.y + w3 * m3.y;
        r.z = w1 * m1.z + w2 * m2.z + w3 * m3.z;
        r.w = w1 * m1.w + w2 * m2.w + w3 * m3.w;
        orow[(size_t)i * H4] = r;
        m1 = m2; m2 = m3; m3 = nxt;
    }
}

extern "C" void kernel_launch(void* const* d_in, const int* in_sizes, int n_in,
                              void* d_out, int out_size, void* d_ws, size_t ws_size,
                              hipStream_t stream) {
    const float* hidden = (const float*)d_in[0];  // [4,B,S,H] f32
    const int* spans    = (const int*)d_in[1];    // [B,S] i32
    const int* masks    = (const int*)d_in[2];    // [B,S] i32
    float* out          = (float*)d_out;          // [B,S,H] f32

    dim3 grid(NSC, NHS, BB);  // 16 x 3 x 16 = 768 single-wave blocks
    span_pool_kernel<<<grid, dim3(64), 0, stream>>>(hidden, spans, masks, out);
}